// Round 6
// baseline (394.874 us; speedup 1.0000x reference)
//
#include <hip/hip_runtime.h>
#include <hip/hip_bf16.h>
#include <hip/hip_fp16.h>

// VoxelMorph flow pipeline. features [16,128^3] f32, label [128^3] f32,
// weight [3,16,3,3,3] f32, bias[3] f32 -> moved [128^3], flow [3,128^3].
//
// R5b: conv in packed fp16 (v_pk_fma_f16 full-rate = 2 MAC/lane/cyc, floor
// 17 us vs 35 us fp32) with z-contiguous half2 LDS columns (stride 5 dwords
// -> conflict-free, half the LDS instructions). Weights ~N(0,1e-5) are
// fp16-subnormal -> pre-scaled x1024 (exact) by pack_weights, descaled in the
// epilogue. Tail (f2/f3/f4) unchanged; testing the fixed-overhead hypothesis.

#define V128 2097152      // 128^3
#define V64  262144       // 64^3

typedef __fp16 __attribute__((ext_vector_type(2))) half2_raw;

// ---------------- trilinear sampler (matches reference _sample) -------------
template <int C>
__device__ __forceinline__ void trisample(const float* __restrict__ vol,
                                          int D, int H, int W, int cstride,
                                          float cz, float cy, float cx,
                                          float* out) {
    float fz = floorf(cz), fy = floorf(cy), fx = floorf(cx);
    int iz = (int)fz, iy = (int)fy, ix = (int)fx;
    float tz = cz - fz, ty = cy - fy, tx = cx - fx;
#pragma unroll
    for (int c = 0; c < C; ++c) out[c] = 0.0f;
#pragma unroll
    for (int dz = 0; dz < 2; ++dz) {
#pragma unroll
        for (int dy = 0; dy < 2; ++dy) {
#pragma unroll
            for (int dx = 0; dx < 2; ++dx) {
                int z = iz + dz, y = iy + dy, x = ix + dx;
                float w = (dz ? tz : 1.0f - tz) *
                          (dy ? ty : 1.0f - ty) *
                          (dx ? tx : 1.0f - tx);
                bool valid = (z >= 0) && (z < D) && (y >= 0) && (y < H) &&
                             (x >= 0) && (x < W);
                int zc = min(max(z, 0), D - 1);
                int yc = min(max(y, 0), H - 1);
                int xc = min(max(x, 0), W - 1);
                int base = (zc * H + yc) * W + xc;
                float wv = valid ? w : 0.0f;
#pragma unroll
                for (int c = 0; c < C; ++c)
                    out[c] += vol[c * cstride + base] * wv;
            }
        }
    }
}

// ---------------- weight pre-pack: f32 -> broadcast half2, x1024 -----------
// Layout: wpk[c*81 + (dy*3+dx)*9 + o*3 + dz], each dword = half2(w,w).
__global__ __launch_bounds__(256) void pack_weights(
    const float* __restrict__ w, unsigned* __restrict__ wpk) {
    int i = blockIdx.x * 256 + threadIdx.x;
    if (i < 1296) {
        int c = i / 81, r = i % 81;
        int t = r / 9, rr = r % 9;
        int o = rr / 3, dz = rr % 3;
        int dy = t / 3, dx = t % 3;
        float wv = w[(o * 16 + c) * 27 + dz * 9 + dy * 3 + dx] * 1024.0f;
        half2_raw p = __builtin_amdgcn_cvt_pkrtz(wv, wv);
        wpk[i] = __builtin_bit_cast(unsigned, p);
    }
}

// ---------------- K1: conv3d 16->3, 3x3x3, pad 1, packed fp16 --------------
// Tile 32(x) x 4(y) x 8(z), 128 threads (thread = (lx,ly), 8 z-outputs).
// Halo = 34x6 columns of 10 z-values, stored as 5 half2 dwords per column
// (stride 5 -> conflict-free LDS). Double-buffered, 1 barrier/channel.
__global__ __launch_bounds__(128) void conv_kernel(
    const float* __restrict__ feat, const unsigned* __restrict__ wpk,
    const float* __restrict__ bias, float* __restrict__ pos_flow) {
    __shared__ unsigned smem[2][1020];  // 204 cols x 5 dwords
    const int tid = threadIdx.x;
    const int x0 = blockIdx.x * 32, y0 = blockIdx.y * 4, z0 = blockIdx.z * 8;
    const int lx = tid & 31, ly = tid >> 5;  // ly in 0..3

    // staging descriptors: 204 columns in <=2 rounds of 128
    int coloff[2];
    bool cval[2];
#pragma unroll
    for (int s = 0; s < 2; ++s) {
        int cc = tid + 128 * s;
        cval[s] = false;
        coloff[s] = 0;
        if (cc < 204) {
            int xx = cc % 34, yy = cc / 34;
            int gx = x0 + xx - 1, gy = y0 + yy - 1;
            cval[s] = ((unsigned)gx < 128u) && ((unsigned)gy < 128u);
            coloff[s] = (min(max(gy, 0), 127) << 7) + min(max(gx, 0), 127);
        }
    }

    __half2 acc2[3][4];
#pragma unroll
    for (int o = 0; o < 3; ++o)
#pragma unroll
        for (int p = 0; p < 4; ++p)
            acc2[o][p] = __builtin_bit_cast(__half2, 0u);

    // stage channel ch into buf
    auto stage = [&](int ch, unsigned* buf) {
        const float* fc = feat + (ch << 21);
#pragma unroll
        for (int s = 0; s < 2; ++s) {
            int cc = tid + 128 * s;
            if (cc < 204) {
                float v[10];
#pragma unroll
                for (int k = 0; k < 10; ++k) {
                    int gz = z0 - 1 + k;
                    int gzc = min(max(gz, 0), 127);
                    float t = fc[(gzc << 14) + coloff[s]];
                    v[k] = (cval[s] && ((unsigned)gz < 128u)) ? t : 0.0f;
                }
#pragma unroll
                for (int j = 0; j < 5; ++j) {
                    half2_raw p =
                        __builtin_amdgcn_cvt_pkrtz(v[2 * j], v[2 * j + 1]);
                    buf[cc * 5 + j] = __builtin_bit_cast(unsigned, p);
                }
            }
        }
    };

    stage(0, smem[0]);

    for (int c = 0; c < 16; ++c) {
        __syncthreads();
        if (c + 1 < 16) stage(c + 1, smem[(c + 1) & 1]);
        const unsigned* buf = smem[c & 1];
        const unsigned* wc = wpk + c * 81;
#pragma unroll
        for (int dy = 0; dy < 3; ++dy) {
#pragma unroll
            for (int dx = 0; dx < 3; ++dx) {
                int cc = (ly + dy) * 34 + (lx + dx);
                unsigned h0 = buf[cc * 5 + 0];
                unsigned h1 = buf[cc * 5 + 1];
                unsigned h2 = buf[cc * 5 + 2];
                unsigned h3 = buf[cc * 5 + 3];
                unsigned h4 = buf[cc * 5 + 4];
                // z pairs: hK = (v[2K], v[2K+1]); shifted pairs for dz=1
                unsigned s0 = (h1 << 16) | (h0 >> 16);  // (v1,v2)
                unsigned s1 = (h2 << 16) | (h1 >> 16);  // (v3,v4)
                unsigned s2 = (h3 << 16) | (h2 >> 16);  // (v5,v6)
                unsigned s3 = (h4 << 16) | (h3 >> 16);  // (v7,v8)
                const int tb = (dy * 3 + dx) * 9;
#pragma unroll
                for (int o = 0; o < 3; ++o) {
                    __half2 w0 = __builtin_bit_cast(__half2, wc[tb + o * 3]);
                    __half2 w1 =
                        __builtin_bit_cast(__half2, wc[tb + o * 3 + 1]);
                    __half2 w2 =
                        __builtin_bit_cast(__half2, wc[tb + o * 3 + 2]);
                    // dz=0: pairs h0..h3; dz=1: s0..s3; dz=2: h1..h4
                    acc2[o][0] = __hfma2(__builtin_bit_cast(__half2, h0), w0,
                                         acc2[o][0]);
                    acc2[o][1] = __hfma2(__builtin_bit_cast(__half2, h1), w0,
                                         acc2[o][1]);
                    acc2[o][2] = __hfma2(__builtin_bit_cast(__half2, h2), w0,
                                         acc2[o][2]);
                    acc2[o][3] = __hfma2(__builtin_bit_cast(__half2, h3), w0,
                                         acc2[o][3]);
                    acc2[o][0] = __hfma2(__builtin_bit_cast(__half2, s0), w1,
                                         acc2[o][0]);
                    acc2[o][1] = __hfma2(__builtin_bit_cast(__half2, s1), w1,
                                         acc2[o][1]);
                    acc2[o][2] = __hfma2(__builtin_bit_cast(__half2, s2), w1,
                                         acc2[o][2]);
                    acc2[o][3] = __hfma2(__builtin_bit_cast(__half2, s3), w1,
                                         acc2[o][3]);
                    acc2[o][0] = __hfma2(__builtin_bit_cast(__half2, h1), w2,
                                         acc2[o][0]);
                    acc2[o][1] = __hfma2(__builtin_bit_cast(__half2, h2), w2,
                                         acc2[o][1]);
                    acc2[o][2] = __hfma2(__builtin_bit_cast(__half2, h3), w2,
                                         acc2[o][2]);
                    acc2[o][3] = __hfma2(__builtin_bit_cast(__half2, h4), w2,
                                         acc2[o][3]);
                }
            }
        }
    }

    const float ds = 1.0f / 1024.0f;
#pragma unroll
    for (int o = 0; o < 3; ++o) {
        float b = bias[o];
        int base = o * V128 + ((y0 + ly) << 7) + x0 + lx;
#pragma unroll
        for (int p = 0; p < 4; ++p) {
            int z = z0 + 2 * p;
            pos_flow[base + (z << 14)] = __low2float(acc2[o][p]) * ds + b;
            pos_flow[base + ((z + 1) << 14)] =
                __high2float(acc2[o][p]) * ds + b;
        }
    }
}

// -------- LDS trilerp, 3 channels, no bounds checks ------------------------
template <int SI>
__device__ __forceinline__ void lds_lerp3(const float* __restrict__ f,
                                          float pz, float py, float px,
                                          float* out) {
    constexpr int NI = SI * SI * SI;
    float fz = floorf(pz), fy = floorf(py), fx = floorf(px);
    int iz = (int)fz, iy = (int)fy, ix = (int)fx;
    float tz = pz - fz, ty = py - fy, tx = px - fx;
    int b = (iz * SI + iy) * SI + ix;
    float wz0 = 1.0f - tz, wy0 = 1.0f - ty, wx0 = 1.0f - tx;
#pragma unroll
    for (int c = 0; c < 3; ++c) {
        const float* fc = f + c * NI;
        float v00 = fc[b] * wx0 + fc[b + 1] * tx;
        float v01 = fc[b + SI] * wx0 + fc[b + SI + 1] * tx;
        float v10 = fc[b + SI * SI] * wx0 + fc[b + SI * SI + 1] * tx;
        float v11 = fc[b + SI * SI + SI] * wx0 + fc[b + SI * SI + SI + 1] * tx;
        out[c] = wz0 * (wy0 * v00 + ty * v01) + tz * (wy0 * v10 + ty * v11);
    }
}

template <int SI>
__device__ __forceinline__ void step_lds(const float* __restrict__ in,
                                         float* __restrict__ out, int tid) {
    constexpr int SO = SI - 2;
    constexpr int NI = SI * SI * SI;
    constexpr int NO = SO * SO * SO;
    for (int i = tid; i < NO; i += 256) {
        int xx = i % SO, yy = (i / SO) % SO, zz = i / (SO * SO);
        int la = ((zz + 1) * SI + (yy + 1)) * SI + (xx + 1);
        float fz = in[la], fy = in[la + NI], fx = in[la + 2 * NI];
        float sm[3];
        lds_lerp3<SI>(in, (zz + 1) + fz, (yy + 1) + fy, (xx + 1) + fx, sm);
        out[i] = fz + sm[0];
        out[i + NO] = fy + sm[1];
        out[i + 2 * NO] = fx + sm[2];
    }
}

__device__ __forceinline__ void step_to_global(const float* __restrict__ in,
                                               float* __restrict__ gout,
                                               int tx, int ty, int tz,
                                               int tid) {
    constexpr int SI = 10;
    constexpr int NI = SI * SI * SI;
    for (int i = tid; i < 512; i += 256) {
        int xx = i & 7, yy = (i >> 3) & 7, zz = i >> 6;
        int la = ((zz + 1) * SI + (yy + 1)) * SI + (xx + 1);
        float fz = in[la], fy = in[la + NI], fx = in[la + 2 * NI];
        float sm[3];
        lds_lerp3<SI>(in, (zz + 1) + fz, (yy + 1) + fy, (xx + 1) + fx, sm);
        int n = ((tz + zz) << 12) + ((ty + yy) << 6) + (tx + xx);
        gout[n] = fz + sm[0];
        gout[n + V64] = fy + sm[1];
        gout[n + 2 * V64] = fx + sm[2];
    }
}

// ------- F2: downsample(x1/256) on 14^3 halo region, then steps 1-3 --------
__global__ __launch_bounds__(256) void f2_kernel(
    const float* __restrict__ pos_flow, float* __restrict__ gout) {
    __shared__ float A[3 * 2744];  // 14^3
    __shared__ float B[3 * 1728];  // 12^3
    const int tid = threadIdx.x;
    const int tx = blockIdx.x * 8, ty = blockIdx.y * 8, tz = blockIdx.z * 8;
    const int rbx = tx - 3, rby = ty - 3, rbz = tz - 3;
    const float s2 = 127.0f / 63.0f;
    const float k = 1.0f / 256.0f;
    for (int i = tid; i < 2744; i += 256) {
        int xx = i % 14, yy = (i / 14) % 14, zz = i / 196;
        int gz = rbz + zz, gy = rby + yy, gx = rbx + xx;
        float v[3] = {0.0f, 0.0f, 0.0f};
        if ((unsigned)gz < 64u && (unsigned)gy < 64u && (unsigned)gx < 64u)
            trisample<3>(pos_flow, 128, 128, 128, V128, gz * s2, gy * s2,
                         gx * s2, v);
        A[i] = v[0] * k;
        A[i + 2744] = v[1] * k;
        A[i + 2 * 2744] = v[2] * k;
    }
    __syncthreads();
    step_lds<14>(A, B, tid);
    __syncthreads();
    step_lds<12>(B, A, tid);
    __syncthreads();
    step_to_global(A, gout, tx, ty, tz, tid);
}

// ------- F3: steps 4-6 ------------------------------------------------------
__global__ __launch_bounds__(256) void f3_kernel(
    const float* __restrict__ gin, float* __restrict__ gout) {
    __shared__ float A[3 * 2744];
    __shared__ float B[3 * 1728];
    const int tid = threadIdx.x;
    const int tx = blockIdx.x * 8, ty = blockIdx.y * 8, tz = blockIdx.z * 8;
    const int rbx = tx - 3, rby = ty - 3, rbz = tz - 3;
    for (int i = tid; i < 2744; i += 256) {
        int xx = i % 14, yy = (i / 14) % 14, zz = i / 196;
        int gz = rbz + zz, gy = rby + yy, gx = rbx + xx;
        float v0 = 0.0f, v1 = 0.0f, v2 = 0.0f;
        if ((unsigned)gz < 64u && (unsigned)gy < 64u && (unsigned)gx < 64u) {
            int n = (gz << 12) + (gy << 6) + gx;
            v0 = gin[n];
            v1 = gin[n + V64];
            v2 = gin[n + 2 * V64];
        }
        A[i] = v0;
        A[i + 2744] = v1;
        A[i + 2 * 2744] = v2;
    }
    __syncthreads();
    step_lds<14>(A, B, tid);
    __syncthreads();
    step_lds<12>(B, A, tid);
    __syncthreads();
    step_to_global(A, gout, tx, ty, tz, tid);
}

// ------- F4: step 7 + upsample(x2) -> flow + label warp -> moved -----------
__global__ __launch_bounds__(256) void f4_kernel(
    const float* __restrict__ gin, const float* __restrict__ label,
    float* __restrict__ moved, float* __restrict__ flow) {
    __shared__ float A[3 * 2197];  // 13^3
    __shared__ float B[3 * 1331];  // 11^3
    const int tid = threadIdx.x;
    const int ttx = blockIdx.x, tty = blockIdx.y, ttz = blockIdx.z;
    const int r0x = (1008 * ttx) / 127 - 1;
    const int r0y = (1008 * tty) / 127 - 1;
    const int r0z = (1008 * ttz) / 127 - 1;
    const int rbx = r0x - 1, rby = r0y - 1, rbz = r0z - 1;
    for (int i = tid; i < 2197; i += 256) {
        int xx = i % 13, yy = (i / 13) % 13, zz = i / 169;
        int gz = rbz + zz, gy = rby + yy, gx = rbx + xx;
        float v0 = 0.0f, v1 = 0.0f, v2 = 0.0f;
        if ((unsigned)gz < 64u && (unsigned)gy < 64u && (unsigned)gx < 64u) {
            int n = (gz << 12) + (gy << 6) + gx;
            v0 = gin[n];
            v1 = gin[n + V64];
            v2 = gin[n + 2 * V64];
        }
        A[i] = v0;
        A[i + 2197] = v1;
        A[i + 2 * 2197] = v2;
    }
    __syncthreads();
    step_lds<13>(A, B, tid);
    __syncthreads();
    const float s3 = 63.0f / 127.0f;
    for (int i = tid; i < 4096; i += 256) {
        int lx = i & 15, ly = (i >> 4) & 15, lz = i >> 8;
        int gx = ttx * 16 + lx, gy = tty * 16 + ly, gz = ttz * 16 + lz;
        float f[3];
        lds_lerp3<11>(B, gz * s3 - (float)r0z, gy * s3 - (float)r0y,
                      gx * s3 - (float)r0x, f);
        float fz = 2.0f * f[0], fy = 2.0f * f[1], fx = 2.0f * f[2];
        int m = (gz << 14) + (gy << 7) + gx;
        flow[m] = fz;
        flow[m + V128] = fy;
        flow[m + 2 * V128] = fx;
        float mv[1];
        trisample<1>(label, 128, 128, 128, 0, gz + fz, gy + fy, gx + fx, mv);
        moved[m] = mv[0];
    }
}

extern "C" void kernel_launch(void* const* d_in, const int* in_sizes, int n_in,
                              void* d_out, int out_size, void* d_ws,
                              size_t ws_size, hipStream_t stream) {
    const float* features = (const float*)d_in[0];
    const float* label = (const float*)d_in[1];
    const float* weight = (const float*)d_in[2];
    const float* bias = (const float*)d_in[3];
    float* out = (float*)d_out;
    float* moved = out;        // 128^3; first 1296 dwords double as wpk scratch
    float* flow = out + V128;  // 3*128^3; also pos_flow scratch
    float* fA = (float*)d_ws;  // 3*64^3 (g3)
    float* fB = fA + 3 * V64;  // 3*64^3 (g6)
    unsigned* wpk = (unsigned*)moved;  // 1296 dwords, consumed by conv, then
                                       // overwritten by f4's moved-write

    pack_weights<<<6, 256, 0, stream>>>(weight, wpk);
    conv_kernel<<<dim3(4, 32, 16), 128, 0, stream>>>(features, wpk, bias,
                                                     flow);
    f2_kernel<<<dim3(8, 8, 8), 256, 0, stream>>>(flow, fA);
    f3_kernel<<<dim3(8, 8, 8), 256, 0, stream>>>(fA, fB);
    f4_kernel<<<dim3(8, 8, 8), 256, 0, stream>>>(fB, label, moved, flow);
}